// Round 1
// baseline (1154.526 us; speedup 1.0000x reference)
//
#include <hip/hip_runtime.h>

// GCN forward: mid = relu(spmm(A, x@W1) + b1); out = spmm(A, mid@W2) + b2
// N=100000 nodes, F=512, H=256, C=40, E=3.2M edges.
//
// Plan:
//  1) memset counts/cursor
//  2) conv_w: W1 -> W1T bf16 [256][512], W2 -> W2T bf16 [48][256] (cols 40..47 = 0)
//  3) hist + scan + scatter: build CSR (row_ptr, scol, sval) on device
//  4) gemm1: bf16 MFMA 16x16x32, T1 = bf16(x@W1)  [N][256]
//  5) spmm1: wave per row, gather bf16 T1 rows, +b1, relu -> mid (fp32, d_out)
//  6) gemm2: bf16 MFMA, T2 = fp32(mid@W2)  [N][40]
//  7) spmm2: wave per row (lanes 0..39), gather fp32 T2 rows, +b2 -> out (d_out)

typedef __bf16 bf16;
typedef __bf16 bf16x8 __attribute__((ext_vector_type(8)));
typedef float floatx4 __attribute__((ext_vector_type(4)));

// ---------------- weight conversion ----------------
__global__ __launch_bounds__(256) void conv_w(const float* __restrict__ W1,
                                              const float* __restrict__ W2,
                                              bf16* __restrict__ W1T,
                                              bf16* __restrict__ W2T) {
  int i = blockIdx.x * 256 + threadIdx.x;
  if (i < 512 * 256) {             // W1 [512][256] -> W1T [256][512]
    int k = i >> 8, n = i & 255;
    W1T[n * 512 + k] = (bf16)W1[i];
  }
  int j = i - 512 * 256;
  if (j >= 0 && j < 48 * 256) {    // W2 [256][40] -> W2T [48][256], pad rows 40..47
    int n = j >> 8, k = j & 255;
    W2T[j] = (n < 40) ? (bf16)W2[k * 40 + n] : (bf16)0.0f;
  }
}

// ---------------- CSR build ----------------
__global__ __launch_bounds__(256) void hist_kernel(const int* __restrict__ er,
                                                   int* __restrict__ counts, int E) {
  int i = blockIdx.x * 256 + threadIdx.x;
  if (i < E) atomicAdd(&counts[er[i]], 1);
}

// single-block exclusive scan: row_ptr[0]=0, row_ptr[i+1]=sum(counts[0..i])
__global__ __launch_bounds__(1024) void scan_kernel(const int* __restrict__ counts,
                                                    int* __restrict__ row_ptr, int Nn) {
  __shared__ int wsum[16];
  const int t = threadIdx.x;
  const int wave = t >> 6, lane = t & 63;
  int running = 0;  // identical across threads
  if (t == 0) row_ptr[0] = 0;
  for (int base = 0; base < Nn; base += 4096) {
    int gi = base + t * 4;
    int4 v = {0, 0, 0, 0};
    if (gi + 3 < Nn) {
      v = *(const int4*)(counts + gi);
    } else {
      if (gi < Nn)     v.x = counts[gi];
      if (gi + 1 < Nn) v.y = counts[gi + 1];
      if (gi + 2 < Nn) v.z = counts[gi + 2];
      if (gi + 3 < Nn) v.w = counts[gi + 3];
    }
    int s = v.x + v.y + v.z + v.w;
    int incl = s;
#pragma unroll
    for (int d = 1; d < 64; d <<= 1) {
      int o = __shfl_up(incl, d, 64);
      if (lane >= d) incl += o;
    }
    if (lane == 63) wsum[wave] = incl;
    __syncthreads();
    int wave_off = 0, tot = 0;
#pragma unroll
    for (int w = 0; w < 16; w++) {
      int xw = wsum[w];
      tot += xw;
      if (w < wave) wave_off += xw;
    }
    int p = running + wave_off + (incl - s);
    p += v.x; if (gi     < Nn) row_ptr[gi + 1] = p;
    p += v.y; if (gi + 1 < Nn) row_ptr[gi + 2] = p;
    p += v.z; if (gi + 2 < Nn) row_ptr[gi + 3] = p;
    p += v.w; if (gi + 3 < Nn) row_ptr[gi + 4] = p;
    running += tot;
    __syncthreads();  // protect wsum for next chunk
  }
}

__global__ __launch_bounds__(256) void scatter_kernel(
    const int* __restrict__ er, const int* __restrict__ ec, const float* __restrict__ ev,
    const int* __restrict__ row_ptr, int* __restrict__ cursor,
    int* __restrict__ scol, float* __restrict__ sval, int E) {
  int i = blockIdx.x * 256 + threadIdx.x;
  if (i < E) {
    int r = er[i];
    int p = row_ptr[r] + atomicAdd(&cursor[r], 1);
    scol[p] = ec[i];
    sval[p] = ev[i];
  }
}

// ---------------- GEMM1: T1 = bf16(x @ W1), [M][256] ----------------
// block: 256 threads = 4 waves; tile BM=64, BN=256, BK=32; wave w -> rows w*16..+15
__global__ __launch_bounds__(256) void gemm1_kernel(const float* __restrict__ x,
                                                    const bf16* __restrict__ W1T,
                                                    bf16* __restrict__ T1, int M) {
  __shared__ __align__(16) bf16 As[64][40];   // +8 pad: 80B stride, 2-way banks (free)
  __shared__ __align__(16) bf16 Bs[256][40];
  const int t = threadIdx.x;
  const int wave = t >> 6, lane = t & 63;
  const int quad = lane >> 4, l16 = lane & 15;
  const int m0 = blockIdx.x * 64;
  floatx4 acc[16] = {};

  const int ar = t >> 2, aq = t & 3;  // A staging: row ar, 8 floats at col aq*8
  const int a_gr = m0 + ar;
  const float* a_src = x + (size_t)a_gr * 512 + aq * 8;
  const bf16* b_src = W1T + (size_t)t * 512;

  for (int k0 = 0; k0 < 512; k0 += 32) {
    __syncthreads();
    {  // stage A (fp32 -> bf16)
      float4 f0 = {0, 0, 0, 0}, f1 = {0, 0, 0, 0};
      if (a_gr < M) {
        const float4* p = (const float4*)(a_src + k0);
        f0 = p[0]; f1 = p[1];
      }
      bf16x8 av;
      av[0] = (bf16)f0.x; av[1] = (bf16)f0.y; av[2] = (bf16)f0.z; av[3] = (bf16)f0.w;
      av[4] = (bf16)f1.x; av[5] = (bf16)f1.y; av[6] = (bf16)f1.z; av[7] = (bf16)f1.w;
      *(bf16x8*)&As[ar][aq * 8] = av;
    }
    {  // stage B: thread t owns row n=t (32 bf16)
      const bf16* p = b_src + k0;
      bf16x8 q0 = *(const bf16x8*)(p);
      bf16x8 q1 = *(const bf16x8*)(p + 8);
      bf16x8 q2 = *(const bf16x8*)(p + 16);
      bf16x8 q3 = *(const bf16x8*)(p + 24);
      *(bf16x8*)&Bs[t][0]  = q0;
      *(bf16x8*)&Bs[t][8]  = q1;
      *(bf16x8*)&Bs[t][16] = q2;
      *(bf16x8*)&Bs[t][24] = q3;
    }
    __syncthreads();
    bf16x8 a = *(const bf16x8*)&As[wave * 16 + l16][quad * 8];
#pragma unroll
    for (int nt = 0; nt < 16; nt++) {
      bf16x8 b = *(const bf16x8*)&Bs[nt * 16 + l16][quad * 8];
      acc[nt] = __builtin_amdgcn_mfma_f32_16x16x32_bf16(a, b, acc[nt], 0, 0, 0);
    }
  }
  // epilogue: D[row=quad*4+j][col=l16] per 16x16 tile
  const int row_base = m0 + wave * 16 + quad * 4;
#pragma unroll
  for (int nt = 0; nt < 16; nt++) {
#pragma unroll
    for (int j = 0; j < 4; j++) {
      int gr = row_base + j;
      if (gr < M) T1[(size_t)gr * 256 + nt * 16 + l16] = (bf16)acc[nt][j];
    }
  }
}

// ---------------- SpMM1: mid = relu(gather-sum(T1) + b1) ----------------
__global__ __launch_bounds__(256) void spmm1_kernel(
    const int* __restrict__ row_ptr, const int* __restrict__ scol,
    const float* __restrict__ sval, const unsigned short* __restrict__ T1,
    const float* __restrict__ b1, float* __restrict__ mid, int M) {
  const int lane = threadIdx.x & 63;
  const int r = blockIdx.x * 4 + (threadIdx.x >> 6);
  if (r >= M) return;
  int e = row_ptr[r];
  const int eend = row_ptr[r + 1];
  float a0 = 0.f, a1 = 0.f, a2 = 0.f, a3 = 0.f;
  const unsigned int* base = (const unsigned int*)T1 + lane * 2;  // 4 bf16 per lane
  for (; e + 1 < eend; e += 2) {
    int c0 = scol[e], c1 = scol[e + 1];
    float v0 = sval[e], v1 = sval[e + 1];
    uint2 u0 = *(const uint2*)(base + (size_t)c0 * 128);
    uint2 u1 = *(const uint2*)(base + (size_t)c1 * 128);
    a0 += v0 * __uint_as_float(u0.x << 16);
    a1 += v0 * __uint_as_float(u0.x & 0xffff0000u);
    a2 += v0 * __uint_as_float(u0.y << 16);
    a3 += v0 * __uint_as_float(u0.y & 0xffff0000u);
    a0 += v1 * __uint_as_float(u1.x << 16);
    a1 += v1 * __uint_as_float(u1.x & 0xffff0000u);
    a2 += v1 * __uint_as_float(u1.y << 16);
    a3 += v1 * __uint_as_float(u1.y & 0xffff0000u);
  }
  if (e < eend) {
    int c0 = scol[e];
    float v0 = sval[e];
    uint2 u0 = *(const uint2*)(base + (size_t)c0 * 128);
    a0 += v0 * __uint_as_float(u0.x << 16);
    a1 += v0 * __uint_as_float(u0.x & 0xffff0000u);
    a2 += v0 * __uint_as_float(u0.y << 16);
    a3 += v0 * __uint_as_float(u0.y & 0xffff0000u);
  }
  int c = lane * 4;
  float4 o;
  o.x = fmaxf(a0 + b1[c],     0.f);
  o.y = fmaxf(a1 + b1[c + 1], 0.f);
  o.z = fmaxf(a2 + b1[c + 2], 0.f);
  o.w = fmaxf(a3 + b1[c + 3], 0.f);
  *(float4*)(mid + (size_t)r * 256 + c) = o;
}

// ---------------- GEMM2: T2 = fp32(mid @ W2), [M][40] ----------------
__global__ __launch_bounds__(256) void gemm2_kernel(const float* __restrict__ mid,
                                                    const bf16* __restrict__ W2T,
                                                    float* __restrict__ T2, int M) {
  __shared__ __align__(16) bf16 As[64][40];
  __shared__ __align__(16) bf16 Bs[48][40];
  const int t = threadIdx.x;
  const int wave = t >> 6, lane = t & 63;
  const int quad = lane >> 4, l16 = lane & 15;
  const int m0 = blockIdx.x * 64;
  floatx4 acc[3] = {};
  const int ar = t >> 2, aq = t & 3;
  const int a_gr = m0 + ar;
  const float* a_src = mid + (size_t)a_gr * 256 + aq * 8;

  for (int k0 = 0; k0 < 256; k0 += 32) {
    __syncthreads();
    {
      float4 f0 = {0, 0, 0, 0}, f1 = {0, 0, 0, 0};
      if (a_gr < M) {
        const float4* p = (const float4*)(a_src + k0);
        f0 = p[0]; f1 = p[1];
      }
      bf16x8 av;
      av[0] = (bf16)f0.x; av[1] = (bf16)f0.y; av[2] = (bf16)f0.z; av[3] = (bf16)f0.w;
      av[4] = (bf16)f1.x; av[5] = (bf16)f1.y; av[6] = (bf16)f1.z; av[7] = (bf16)f1.w;
      *(bf16x8*)&As[ar][aq * 8] = av;
    }
    if (t < 192) {  // B: 48 rows x 32 bf16
      int n = t >> 2, q = t & 3;
      bf16x8 b = *(const bf16x8*)(W2T + n * 256 + k0 + q * 8);
      *(bf16x8*)&Bs[n][q * 8] = b;
    }
    __syncthreads();
    bf16x8 a = *(const bf16x8*)&As[wave * 16 + l16][quad * 8];
#pragma unroll
    for (int nt = 0; nt < 3; nt++) {
      bf16x8 b = *(const bf16x8*)&Bs[nt * 16 + l16][quad * 8];
      acc[nt] = __builtin_amdgcn_mfma_f32_16x16x32_bf16(a, b, acc[nt], 0, 0, 0);
    }
  }
  const int row_base = m0 + wave * 16 + quad * 4;
#pragma unroll
  for (int nt = 0; nt < 3; nt++) {
#pragma unroll
    for (int j = 0; j < 4; j++) {
      int gr = row_base + j;
      int col = nt * 16 + l16;
      if (gr < M && col < 40) T2[(size_t)gr * 40 + col] = acc[nt][j];
    }
  }
}

// ---------------- SpMM2: out = gather-sum(T2) + b2 ----------------
__global__ __launch_bounds__(256) void spmm2_kernel(
    const int* __restrict__ row_ptr, const int* __restrict__ scol,
    const float* __restrict__ sval, const float* __restrict__ T2,
    const float* __restrict__ b2, float* __restrict__ out2, int M) {
  const int lane = threadIdx.x & 63;
  const int r = blockIdx.x * 4 + (threadIdx.x >> 6);
  if (r >= M || lane >= 40) return;
  int e = row_ptr[r];
  const int eend = row_ptr[r + 1];
  float acc = 0.f, acc2 = 0.f;
  for (; e + 1 < eend; e += 2) {
    int c0 = scol[e], c1 = scol[e + 1];
    float v0 = sval[e], v1 = sval[e + 1];
    acc  += v0 * T2[(size_t)c0 * 40 + lane];
    acc2 += v1 * T2[(size_t)c1 * 40 + lane];
  }
  if (e < eend) acc += sval[e] * T2[(size_t)scol[e] * 40 + lane];
  out2[(size_t)r * 40 + lane] = acc + acc2 + b2[lane];
}

// ---------------- launch ----------------
extern "C" void kernel_launch(void* const* d_in, const int* in_sizes, int n_in,
                              void* d_out, int out_size, void* d_ws, size_t ws_size,
                              hipStream_t stream) {
  const float* x        = (const float*)d_in[0];
  const int*   edge_row = (const int*)d_in[1];
  const int*   edge_col = (const int*)d_in[2];
  const float* edge_val = (const float*)d_in[3];
  const float* W1       = (const float*)d_in[4];
  const float* b1       = (const float*)d_in[5];
  const float* W2       = (const float*)d_in[6];
  const float* b2       = (const float*)d_in[7];
  const int M = in_sizes[0] / 512;  // 100000 nodes
  const int E = in_sizes[1];        // 3200000 edges

  char* ws = (char*)d_ws;
  size_t off = 0;
  bf16* T1      = (bf16*)(ws + off);  off += (size_t)M * 256 * 2;
  bf16* W1T     = (bf16*)(ws + off);  off += 512 * 256 * 2;
  bf16* W2T     = (bf16*)(ws + off);  off += 48 * 256 * 2;
  float* T2     = (float*)(ws + off); off += (size_t)M * 40 * 4;
  int* counts   = (int*)(ws + off);   off += (size_t)M * 4;
  int* cursor   = (int*)(ws + off);   off += (size_t)M * 4;
  int* row_ptr  = (int*)(ws + off);   off += ((size_t)M + 1) * 4;
  off = (off + 15) & ~(size_t)15;
  int* scol     = (int*)(ws + off);   off += (size_t)E * 4;
  float* sval   = (float*)(ws + off); off += (size_t)E * 4;

  float* mid  = (float*)d_out;
  float* out2 = mid + (size_t)M * 256;

  hipMemsetAsync(counts, 0, (size_t)M * 8, stream);  // counts + cursor (adjacent)

  conv_w<<<(512 * 256 + 48 * 256 + 255) / 256, 256, 0, stream>>>(W1, W2, W1T, W2T);
  hist_kernel<<<(E + 255) / 256, 256, 0, stream>>>(edge_row, counts, E);
  scan_kernel<<<1, 1024, 0, stream>>>(counts, row_ptr, M);
  scatter_kernel<<<(E + 255) / 256, 256, 0, stream>>>(edge_row, edge_col, edge_val,
                                                      row_ptr, cursor, scol, sval, E);
  gemm1_kernel<<<(M + 63) / 64, 256, 0, stream>>>(x, W1T, T1, M);
  spmm1_kernel<<<(M + 3) / 4, 256, 0, stream>>>(row_ptr, scol, sval,
                                                (const unsigned short*)T1, b1, mid, M);
  gemm2_kernel<<<(M + 63) / 64, 256, 0, stream>>>(mid, W2T, T2, M);
  spmm2_kernel<<<(M + 3) / 4, 256, 0, stream>>>(row_ptr, scol, sval, T2, b2, out2, M);
}

// Round 2
// 1086.454 us; speedup vs baseline: 1.0627x; 1.0627x over previous
//
#include <hip/hip_runtime.h>

// GCN forward: mid = relu(spmm(A, x@W1) + b1); out = spmm(A, mid@W2) + b2
// N=100000, F=512, H=256, C=40, E=3.2M.
//
// R2 changes vs R1:
//  - epack: (col, val) int2 per edge (single 8B store/load)
//  - spmm1: unroll x4, float4 bias load
//  - T2 stored bf16 padded stride 64 (128B rows); spmm2 does 2 edges/iter
//    (half-wave each) + shfl combine; gather bytes halved & aligned
//  - scan: single-chunk-per-thread single-block scan (no serialized rounds)

typedef __bf16 bf16;
typedef __bf16 bf16x8 __attribute__((ext_vector_type(8)));
typedef float floatx4 __attribute__((ext_vector_type(4)));

// ---------------- weight conversion ----------------
__global__ __launch_bounds__(256) void conv_w(const float* __restrict__ W1,
                                              const float* __restrict__ W2,
                                              bf16* __restrict__ W1T,
                                              bf16* __restrict__ W2T) {
  int i = blockIdx.x * 256 + threadIdx.x;
  if (i < 512 * 256) {             // W1 [512][256] -> W1T [256][512]
    int k = i >> 8, n = i & 255;
    W1T[n * 512 + k] = (bf16)W1[i];
  }
  int j = i - 512 * 256;
  if (j >= 0 && j < 48 * 256) {    // W2 [256][40] -> W2T [48][256], pad rows 40..47
    int n = j >> 8, k = j & 255;
    W2T[j] = (n < 40) ? (bf16)W2[k * 40 + n] : (bf16)0.0f;
  }
}

// ---------------- CSR build ----------------
__global__ __launch_bounds__(256) void hist_kernel(const int* __restrict__ er,
                                                   int* __restrict__ counts, int E) {
  int i = blockIdx.x * 256 + threadIdx.x;
  if (i < E) atomicAdd(&counts[er[i]], 1);
}

// single-block scan, one contiguous chunk per thread (C ints, C%4==0)
__global__ __launch_bounds__(1024) void scan_kernel(const int* __restrict__ counts,
                                                    int* __restrict__ row_ptr, int Nn) {
  __shared__ int wsum[16];
  const int t = threadIdx.x;
  const int wave = t >> 6, lane = t & 63;
  const int C = (((Nn + 1023) / 1024) + 3) & ~3;
  const int base = t * C;
  // pass A: per-thread sum
  int s = 0;
  for (int k = 0; k < C; k += 4) {
    int gi = base + k;
    if (gi + 3 < Nn) {
      int4 v = *(const int4*)(counts + gi);
      s += v.x + v.y + v.z + v.w;
    } else {
      if (gi     < Nn) s += counts[gi];
      if (gi + 1 < Nn) s += counts[gi + 1];
      if (gi + 2 < Nn) s += counts[gi + 2];
      if (gi + 3 < Nn) s += counts[gi + 3];
    }
  }
  // wave-inclusive scan of thread sums
  int incl = s;
#pragma unroll
  for (int d = 1; d < 64; d <<= 1) {
    int o = __shfl_up(incl, d, 64);
    if (lane >= d) incl += o;
  }
  if (lane == 63) wsum[wave] = incl;
  __syncthreads();
  int wave_off = 0;
#pragma unroll
  for (int w = 0; w < 16; w++) {
    int xw = wsum[w];
    if (w < wave) wave_off += xw;
  }
  int p = wave_off + (incl - s);  // exclusive prefix of this thread's chunk
  if (t == 0) row_ptr[0] = 0;
  // pass B: re-read, write prefixes
  for (int k = 0; k < C; k += 4) {
    int gi = base + k;
    int4 v = {0, 0, 0, 0};
    if (gi + 3 < Nn) {
      v = *(const int4*)(counts + gi);
    } else {
      if (gi     < Nn) v.x = counts[gi];
      if (gi + 1 < Nn) v.y = counts[gi + 1];
      if (gi + 2 < Nn) v.z = counts[gi + 2];
      if (gi + 3 < Nn) v.w = counts[gi + 3];
    }
    p += v.x; if (gi     < Nn) row_ptr[gi + 1] = p;
    p += v.y; if (gi + 1 < Nn) row_ptr[gi + 2] = p;
    p += v.z; if (gi + 2 < Nn) row_ptr[gi + 3] = p;
    p += v.w; if (gi + 3 < Nn) row_ptr[gi + 4] = p;
  }
}

__global__ __launch_bounds__(256) void scatter_kernel(
    const int* __restrict__ er, const int* __restrict__ ec, const float* __restrict__ ev,
    const int* __restrict__ row_ptr, int* __restrict__ cursor,
    int2* __restrict__ epack, int E) {
  int i = blockIdx.x * 256 + threadIdx.x;
  if (i < E) {
    int r = er[i];
    int p = row_ptr[r] + atomicAdd(&cursor[r], 1);
    int2 m;
    m.x = ec[i];
    m.y = __float_as_int(ev[i]);
    epack[p] = m;
  }
}

// ---------------- GEMM1: T1 = bf16(x @ W1), [M][256] ----------------
__global__ __launch_bounds__(256) void gemm1_kernel(const float* __restrict__ x,
                                                    const bf16* __restrict__ W1T,
                                                    bf16* __restrict__ T1, int M) {
  __shared__ __align__(16) bf16 As[64][40];
  __shared__ __align__(16) bf16 Bs[256][40];
  const int t = threadIdx.x;
  const int wave = t >> 6, lane = t & 63;
  const int quad = lane >> 4, l16 = lane & 15;
  const int m0 = blockIdx.x * 64;
  floatx4 acc[16] = {};

  const int ar = t >> 2, aq = t & 3;
  const int a_gr = m0 + ar;
  const float* a_src = x + (size_t)a_gr * 512 + aq * 8;
  const bf16* b_src = W1T + (size_t)t * 512;

  for (int k0 = 0; k0 < 512; k0 += 32) {
    __syncthreads();
    {
      float4 f0 = {0, 0, 0, 0}, f1 = {0, 0, 0, 0};
      if (a_gr < M) {
        const float4* p = (const float4*)(a_src + k0);
        f0 = p[0]; f1 = p[1];
      }
      bf16x8 av;
      av[0] = (bf16)f0.x; av[1] = (bf16)f0.y; av[2] = (bf16)f0.z; av[3] = (bf16)f0.w;
      av[4] = (bf16)f1.x; av[5] = (bf16)f1.y; av[6] = (bf16)f1.z; av[7] = (bf16)f1.w;
      *(bf16x8*)&As[ar][aq * 8] = av;
    }
    {
      const bf16* p = b_src + k0;
      bf16x8 q0 = *(const bf16x8*)(p);
      bf16x8 q1 = *(const bf16x8*)(p + 8);
      bf16x8 q2 = *(const bf16x8*)(p + 16);
      bf16x8 q3 = *(const bf16x8*)(p + 24);
      *(bf16x8*)&Bs[t][0]  = q0;
      *(bf16x8*)&Bs[t][8]  = q1;
      *(bf16x8*)&Bs[t][16] = q2;
      *(bf16x8*)&Bs[t][24] = q3;
    }
    __syncthreads();
    bf16x8 a = *(const bf16x8*)&As[wave * 16 + l16][quad * 8];
#pragma unroll
    for (int nt = 0; nt < 16; nt++) {
      bf16x8 b = *(const bf16x8*)&Bs[nt * 16 + l16][quad * 8];
      acc[nt] = __builtin_amdgcn_mfma_f32_16x16x32_bf16(a, b, acc[nt], 0, 0, 0);
    }
  }
  const int row_base = m0 + wave * 16 + quad * 4;
#pragma unroll
  for (int nt = 0; nt < 16; nt++) {
#pragma unroll
    for (int j = 0; j < 4; j++) {
      int gr = row_base + j;
      if (gr < M) T1[(size_t)gr * 256 + nt * 16 + l16] = (bf16)acc[nt][j];
    }
  }
}

// ---------------- SpMM1: mid = relu(gather-sum(T1) + b1) ----------------
__device__ __forceinline__ float bflo(unsigned int u) { return __uint_as_float(u << 16); }
__device__ __forceinline__ float bfhi(unsigned int u) { return __uint_as_float(u & 0xffff0000u); }

__global__ __launch_bounds__(256) void spmm1_kernel(
    const int* __restrict__ row_ptr, const int2* __restrict__ epack,
    const unsigned int* __restrict__ T1u, const float* __restrict__ b1,
    float* __restrict__ mid, int M) {
  const int lane = threadIdx.x & 63;
  const int r = blockIdx.x * 4 + (threadIdx.x >> 6);
  if (r >= M) return;
  int e = row_ptr[r];
  const int eend = row_ptr[r + 1];
  float a0 = 0.f, a1 = 0.f, a2 = 0.f, a3 = 0.f;
  const unsigned int* base = T1u + lane * 2;  // 4 bf16 per lane, row stride 128 uints
  for (; e + 3 < eend; e += 4) {
    int2 m0 = epack[e], m1 = epack[e + 1], m2 = epack[e + 2], m3 = epack[e + 3];
    uint2 u0 = *(const uint2*)(base + (size_t)m0.x * 128);
    uint2 u1 = *(const uint2*)(base + (size_t)m1.x * 128);
    uint2 u2 = *(const uint2*)(base + (size_t)m2.x * 128);
    uint2 u3 = *(const uint2*)(base + (size_t)m3.x * 128);
    float v0 = __int_as_float(m0.y), v1 = __int_as_float(m1.y);
    float v2 = __int_as_float(m2.y), v3 = __int_as_float(m3.y);
    a0 += v0 * bflo(u0.x); a1 += v0 * bfhi(u0.x); a2 += v0 * bflo(u0.y); a3 += v0 * bfhi(u0.y);
    a0 += v1 * bflo(u1.x); a1 += v1 * bfhi(u1.x); a2 += v1 * bflo(u1.y); a3 += v1 * bfhi(u1.y);
    a0 += v2 * bflo(u2.x); a1 += v2 * bfhi(u2.x); a2 += v2 * bflo(u2.y); a3 += v2 * bfhi(u2.y);
    a0 += v3 * bflo(u3.x); a1 += v3 * bfhi(u3.x); a2 += v3 * bflo(u3.y); a3 += v3 * bfhi(u3.y);
  }
  for (; e < eend; e++) {
    int2 m0 = epack[e];
    float v0 = __int_as_float(m0.y);
    uint2 u0 = *(const uint2*)(base + (size_t)m0.x * 128);
    a0 += v0 * bflo(u0.x); a1 += v0 * bfhi(u0.x); a2 += v0 * bflo(u0.y); a3 += v0 * bfhi(u0.y);
  }
  int c = lane * 4;
  float4 bb = *(const float4*)(b1 + c);
  float4 o;
  o.x = fmaxf(a0 + bb.x, 0.f);
  o.y = fmaxf(a1 + bb.y, 0.f);
  o.z = fmaxf(a2 + bb.z, 0.f);
  o.w = fmaxf(a3 + bb.w, 0.f);
  *(float4*)(mid + (size_t)r * 256 + c) = o;
}

// ---------------- GEMM2: T2p = bf16(mid @ W2), [M][64] (cols 0..39 valid) ----------------
__global__ __launch_bounds__(256) void gemm2_kernel(const float* __restrict__ mid,
                                                    const bf16* __restrict__ W2T,
                                                    bf16* __restrict__ T2p, int M) {
  __shared__ __align__(16) bf16 As[64][40];
  __shared__ __align__(16) bf16 Bs[48][40];
  const int t = threadIdx.x;
  const int wave = t >> 6, lane = t & 63;
  const int quad = lane >> 4, l16 = lane & 15;
  const int m0 = blockIdx.x * 64;
  floatx4 acc[3] = {};
  const int ar = t >> 2, aq = t & 3;
  const int a_gr = m0 + ar;
  const float* a_src = mid + (size_t)a_gr * 256 + aq * 8;

  for (int k0 = 0; k0 < 256; k0 += 32) {
    __syncthreads();
    {
      float4 f0 = {0, 0, 0, 0}, f1 = {0, 0, 0, 0};
      if (a_gr < M) {
        const float4* p = (const float4*)(a_src + k0);
        f0 = p[0]; f1 = p[1];
      }
      bf16x8 av;
      av[0] = (bf16)f0.x; av[1] = (bf16)f0.y; av[2] = (bf16)f0.z; av[3] = (bf16)f0.w;
      av[4] = (bf16)f1.x; av[5] = (bf16)f1.y; av[6] = (bf16)f1.z; av[7] = (bf16)f1.w;
      *(bf16x8*)&As[ar][aq * 8] = av;
    }
    if (t < 192) {
      int n = t >> 2, q = t & 3;
      bf16x8 b = *(const bf16x8*)(W2T + n * 256 + k0 + q * 8);
      *(bf16x8*)&Bs[n][q * 8] = b;
    }
    __syncthreads();
    bf16x8 a = *(const bf16x8*)&As[wave * 16 + l16][quad * 8];
#pragma unroll
    for (int nt = 0; nt < 3; nt++) {
      bf16x8 b = *(const bf16x8*)&Bs[nt * 16 + l16][quad * 8];
      acc[nt] = __builtin_amdgcn_mfma_f32_16x16x32_bf16(a, b, acc[nt], 0, 0, 0);
    }
  }
  const int row_base = m0 + wave * 16 + quad * 4;
#pragma unroll
  for (int nt = 0; nt < 3; nt++) {
#pragma unroll
    for (int j = 0; j < 4; j++) {
      int gr = row_base + j;
      int col = nt * 16 + l16;
      if (gr < M && col < 40) T2p[(size_t)gr * 64 + col] = (bf16)acc[nt][j];
    }
  }
}

// ---------------- SpMM2: out = gather-sum(T2p) + b2 ----------------
// 2 edges per wave-iteration: lanes 0..31 -> edge A, lanes 32..63 -> edge B.
// lane covers cols (2*(lane&31), 2*(lane&31)+1); combine halves via shfl at end.
__global__ __launch_bounds__(256) void spmm2_kernel(
    const int* __restrict__ row_ptr, const int2* __restrict__ epack,
    const unsigned int* __restrict__ T2u,  // bf16 rows, stride 32 uints (128B)
    const float* __restrict__ b2, float* __restrict__ out2, int M) {
  const int lane = threadIdx.x & 63;
  const int r = blockIdx.x * 4 + (threadIdx.x >> 6);
  if (r >= M) return;
  const int l31 = lane & 31;
  const bool hi = lane >= 32;
  int e = row_ptr[r];
  const int eend = row_ptr[r + 1];
  float a0 = 0.f, a1 = 0.f;
  const unsigned int* base = T2u + l31;
  for (; e + 3 < eend; e += 4) {
    int2 m0 = epack[e], m1 = epack[e + 1], m2 = epack[e + 2], m3 = epack[e + 3];
    int cA = hi ? m1.x : m0.x;
    int cB = hi ? m3.x : m2.x;
    float vA = __int_as_float(hi ? m1.y : m0.y);
    float vB = __int_as_float(hi ? m3.y : m2.y);
    unsigned int uA = base[(size_t)cA * 32];
    unsigned int uB = base[(size_t)cB * 32];
    a0 += vA * bflo(uA); a1 += vA * bfhi(uA);
    a0 += vB * bflo(uB); a1 += vB * bfhi(uB);
  }
  for (; e < eend; e += 2) {
    int2 m0 = epack[e];
    int2 m1 = (e + 1 < eend) ? epack[e + 1] : make_int2(0, 0);
    int c = hi ? m1.x : m0.x;
    float v = __int_as_float(hi ? m1.y : m0.y);
    unsigned int u = base[(size_t)c * 32];
    a0 += v * bflo(u); a1 += v * bfhi(u);
  }
  a0 += __shfl_down(a0, 32, 64);
  a1 += __shfl_down(a1, 32, 64);
  if (lane < 20) {
    float2 o;
    o.x = a0 + b2[2 * lane];
    o.y = a1 + b2[2 * lane + 1];
    *(float2*)(out2 + (size_t)r * 40 + 2 * lane) = o;
  }
}

// ---------------- launch ----------------
extern "C" void kernel_launch(void* const* d_in, const int* in_sizes, int n_in,
                              void* d_out, int out_size, void* d_ws, size_t ws_size,
                              hipStream_t stream) {
  const float* x        = (const float*)d_in[0];
  const int*   edge_row = (const int*)d_in[1];
  const int*   edge_col = (const int*)d_in[2];
  const float* edge_val = (const float*)d_in[3];
  const float* W1       = (const float*)d_in[4];
  const float* b1       = (const float*)d_in[5];
  const float* W2       = (const float*)d_in[6];
  const float* b2       = (const float*)d_in[7];
  const int M = in_sizes[0] / 512;  // 100000 nodes
  const int E = in_sizes[1];        // 3200000 edges

  char* ws = (char*)d_ws;
  size_t off = 0;
  bf16* T1      = (bf16*)(ws + off);  off += (size_t)M * 256 * 2;
  bf16* W1T     = (bf16*)(ws + off);  off += 512 * 256 * 2;
  bf16* W2T     = (bf16*)(ws + off);  off += 48 * 256 * 2;
  bf16* T2p     = (bf16*)(ws + off);  off += (size_t)M * 64 * 2;
  int* counts   = (int*)(ws + off);   off += (size_t)M * 4;
  int* cursor   = (int*)(ws + off);   off += (size_t)M * 4;
  int* row_ptr  = (int*)(ws + off);   off += ((size_t)M + 1) * 4;
  off = (off + 15) & ~(size_t)15;
  int2* epack   = (int2*)(ws + off);  off += (size_t)E * 8;

  float* mid  = (float*)d_out;
  float* out2 = mid + (size_t)M * 256;

  hipMemsetAsync(counts, 0, (size_t)M * 8, stream);  // counts + cursor (adjacent)

  conv_w<<<(512 * 256 + 48 * 256 + 255) / 256, 256, 0, stream>>>(W1, W2, W1T, W2T);
  hist_kernel<<<(E + 255) / 256, 256, 0, stream>>>(edge_row, counts, E);
  scan_kernel<<<1, 1024, 0, stream>>>(counts, row_ptr, M);
  scatter_kernel<<<(E + 255) / 256, 256, 0, stream>>>(edge_row, edge_col, edge_val,
                                                      row_ptr, cursor, epack, E);
  gemm1_kernel<<<(M + 63) / 64, 256, 0, stream>>>(x, W1T, T1, M);
  spmm1_kernel<<<(M + 3) / 4, 256, 0, stream>>>(row_ptr, epack,
                                                (const unsigned int*)T1, b1, mid, M);
  gemm2_kernel<<<(M + 63) / 64, 256, 0, stream>>>(mid, W2T, T2p, M);
  spmm2_kernel<<<(M + 3) / 4, 256, 0, stream>>>(row_ptr, epack,
                                                (const unsigned int*)T2p, b2, out2, M);
}